// Round 9
// baseline (30.550 us; speedup 1.0000x reference)
//
#include <hip/hip_runtime.h>

// ---------------------------------------------------------------------------
// Compile-time wavelet-packet response matrix A[64][50]:
// A[j*8+m][n] = coefficient of x[n] in leaf j, sample m (3-level sym2, zero pad).
// Geometry: 50 -> 26 -> 14 -> 8, pad ph=2 both sides at every level (all even).
// ---------------------------------------------------------------------------
struct Amat { float a[64][50]; };

constexpr Amat makeA() {
    constexpr float h0[4] = { 0.48296291314453416f,  0.8365163037378079f,
                              0.22414386804185735f, -0.12940952255126037f};
    constexpr float h1[4] = {-0.12940952255126037f, -0.22414386804185735f,
                              0.8365163037378079f,  -0.48296291314453416f};
    float L1[2][26][50] = {};
    for (int band = 0; band < 2; ++band)
        for (int m = 0; m < 26; ++m)
            for (int n = 0; n < 50; ++n) {
                int k = n - 2 * m + 2;
                L1[band][m][n] = (k >= 0 && k < 4) ? (band ? h1[k] : h0[k]) : 0.0f;
            }
    float L2[4][14][50] = {};
    for (int j = 0; j < 4; ++j)
        for (int m = 0; m < 14; ++m)
            for (int n = 0; n < 50; ++n) {
                float acc = 0.0f;
                for (int k = 0; k < 4; ++k) {
                    int p = 2 * m + k - 2;
                    if (p >= 0 && p < 26)
                        acc += (j & 1 ? h1[k] : h0[k]) * L1[j >> 1][p][n];
                }
                L2[j][m][n] = acc;
            }
    Amat A = {};
    for (int j = 0; j < 8; ++j)
        for (int m = 0; m < 8; ++m)
            for (int n = 0; n < 50; ++n) {
                float acc = 0.0f;
                for (int k = 0; k < 4; ++k) {
                    int p = 2 * m + k - 2;
                    if (p >= 0 && p < 14)
                        acc += (j & 1 ? h1[k] : h0[k]) * L2[j >> 1][p][n];
                }
                A.a[j * 8 + m][n] = acc;
            }
    return A;
}

__device__ __constant__ Amat cA = makeA();

#define SWP 193   // padded LDS stride for W rows (breaks k*192 same-bank pattern)

// 5 fmas of element xv (feature ib, runtime) into the accumulators
#define FMA_EL(xv, ib)                          \
    a0 = fmaf(sM[(ib) * 5 + 0], (xv), a0);      \
    a1 = fmaf(sM[(ib) * 5 + 1], (xv), a1);      \
    a2 = fmaf(sM[(ib) * 5 + 2], (xv), a2);      \
    a3 = fmaf(sM[(ib) * 5 + 3], (xv), a3);      \
    a4 = fmaf(sM[(ib) * 5 + 4], (xv), a4);

// ---------------------------------------------------------------------------
// Fused, 4 threads per row: 2048 blocks x 256 threads (8 blocks/CU,
// 16-32 waves/CU). Lane-quad q=0..3 splits a row's 75 float2 INTERLEAVED
// (quad reads 32 contiguous bytes per step -> line locality). All ~19 loads
// issued before the fold prologue (static reg array) so they fly under it.
// Fold parallelized over all 256 threads (3 (i,k)-pairs each). Quad-reduce
// via shfl_xor(1,2); lane q==0 stores 5 floats.
// ---------------------------------------------------------------------------
__global__ __launch_bounds__(256) void dwt_fused(const float* __restrict__ x,
                                                 const float* __restrict__ W,
                                                 const float* __restrict__ bias,
                                                 float* __restrict__ out) {
    __shared__ float sW[5 * SWP];
    __shared__ float sM[752];        // flat [i*5+k], 750 used
    const int tid = threadIdx.x;
    const size_t g   = (size_t)blockIdx.x * 256 + tid;
    const size_t row = g >> 2;
    const int    q   = (int)(g & 3);

    const float2* __restrict__ xr = (const float2*)(x + row * 150);

    // ---- issue all x loads up front (static indexing -> registers) ----
    float2 v[19];
    #pragma unroll
    for (int j = 0; j < 18; ++j) v[j] = xr[4 * j + q];
    v[18] = xr[(q < 3) ? (72 + q) : 74];          // q==3: dup in-bounds, unused

    // ---- stage W into padded LDS ----
    #pragma unroll
    for (int t = 0; t < 4; ++t) {
        const int idx = tid + t * 256;
        if (idx < 960) sW[(idx / 192) * SWP + (idx % 192)] = W[idx];
    }
    __syncthreads();

    // ---- fold W with cA into sM: thread computes pairs p, p+256, p+512 ----
    #pragma unroll
    for (int t = 0; t < 3; ++t) {
        const int p = tid + t * 256;
        if (p < 750) {
            const int i = p / 5, k = p - 5 * i;     // p = i*5 + k
            const int c = i / 50, n = i - 50 * c;
            float acc = 0.f;
            #pragma unroll 16
            for (int f = 0; f < 64; ++f)            // f = j*8 + s
                acc = fmaf(sW[k * SWP + (f >> 3) * 24 + c * 8 + (f & 7)],
                           cA.a[f][n], acc);
            sM[p] = acc;
        }
    }
    __syncthreads();

    // ---- main: 5-class dot over this thread's quarter of the row ----
    float a0 = 0.f, a1 = 0.f, a2 = 0.f, a3 = 0.f, a4 = 0.f;
    #pragma unroll
    for (int j = 0; j < 18; ++j) {
        const int ib = 2 * (4 * j + q);
        FMA_EL(v[j].x, ib)
        FMA_EL(v[j].y, ib + 1)
    }
    if (q < 3) {
        const int ib = 2 * (72 + q);
        FMA_EL(v[18].x, ib)
        FMA_EL(v[18].y, ib + 1)
    }

    // ---- quad reduction (lanes 4i..4i+3 in same wave) ----
    a0 += __shfl_xor(a0, 1); a0 += __shfl_xor(a0, 2);
    a1 += __shfl_xor(a1, 1); a1 += __shfl_xor(a1, 2);
    a2 += __shfl_xor(a2, 1); a2 += __shfl_xor(a2, 2);
    a3 += __shfl_xor(a3, 1); a3 += __shfl_xor(a3, 2);
    a4 += __shfl_xor(a4, 1); a4 += __shfl_xor(a4, 2);

    if (q == 0) {
        float* o = out + row * 5;
        o[0] = a0 + bias[0];
        o[1] = a1 + bias[1];
        o[2] = a2 + bias[2];
        o[3] = a3 + bias[3];
        o[4] = a4 + bias[4];
    }
}

extern "C" void kernel_launch(void* const* d_in, const int* in_sizes, int n_in,
                              void* d_out, int out_size, void* d_ws, size_t ws_size,
                              hipStream_t stream) {
    const float* x    = (const float*)d_in[0];   // (131072, 3, 50)
    const float* W    = (const float*)d_in[1];   // (5, 192)
    const float* bias = (const float*)d_in[2];   // (5,)
    float*       out  = (float*)d_out;           // (131072, 5)

    const int B = in_sizes[0] / 150;             // 131072
    const int grid = (B * 4) / 256;              // 2048 blocks, 8/CU
    dwt_fused<<<grid, 256, 0, stream>>>(x, W, bias, out);
}

// Round 10
// 25.162 us; speedup vs baseline: 1.2141x; 1.2141x over previous
//
#include <hip/hip_runtime.h>

// ---------------------------------------------------------------------------
// Compile-time wavelet-packet response matrix A[64][50]:
// A[j*8+m][n] = coefficient of x[n] in leaf j, sample m (3-level sym2, zero pad).
// Geometry: 50 -> 26 -> 14 -> 8, pad ph=2 both sides at every level (all even).
// ---------------------------------------------------------------------------
struct Amat { float a[64][50]; };

constexpr Amat makeA() {
    constexpr float h0[4] = { 0.48296291314453416f,  0.8365163037378079f,
                              0.22414386804185735f, -0.12940952255126037f};
    constexpr float h1[4] = {-0.12940952255126037f, -0.22414386804185735f,
                              0.8365163037378079f,  -0.48296291314453416f};
    float L1[2][26][50] = {};
    for (int band = 0; band < 2; ++band)
        for (int m = 0; m < 26; ++m)
            for (int n = 0; n < 50; ++n) {
                int k = n - 2 * m + 2;
                L1[band][m][n] = (k >= 0 && k < 4) ? (band ? h1[k] : h0[k]) : 0.0f;
            }
    float L2[4][14][50] = {};
    for (int j = 0; j < 4; ++j)
        for (int m = 0; m < 14; ++m)
            for (int n = 0; n < 50; ++n) {
                float acc = 0.0f;
                for (int k = 0; k < 4; ++k) {
                    int p = 2 * m + k - 2;
                    if (p >= 0 && p < 26)
                        acc += (j & 1 ? h1[k] : h0[k]) * L1[j >> 1][p][n];
                }
                L2[j][m][n] = acc;
            }
    Amat A = {};
    for (int j = 0; j < 8; ++j)
        for (int m = 0; m < 8; ++m)
            for (int n = 0; n < 50; ++n) {
                float acc = 0.0f;
                for (int k = 0; k < 4; ++k) {
                    int p = 2 * m + k - 2;
                    if (p >= 0 && p < 14)
                        acc += (j & 1 ? h1[k] : h0[k]) * L2[j >> 1][p][n];
                }
                A.a[j * 8 + m][n] = acc;
            }
    return A;
}

__device__ __constant__ Amat cA = makeA();

// ---------------------------------------------------------------------------
// Kernel 1 (1 block): fold W (5x192) + bias into TRANSPOSED padded layout
//   Mgt[k*152 + i] = M[i][k]  (i = c*50+n in [0,150))
//   Mgt[k*152 + 150] = bias[k];  Mgt[k*152 + 151] = 0  (pad)
// W staged to LDS; f-loop unrolled x16 (R7-measured fast, ~2us incl launch).
// ---------------------------------------------------------------------------
__global__ __launch_bounds__(256) void build_M(const float* __restrict__ W,
                                               const float* __restrict__ bias,
                                               float* __restrict__ Mgt) {
    __shared__ float sW[960];
    const int tid = threadIdx.x;
    #pragma unroll
    for (int t = 0; t < 4; ++t) {
        const int idx = tid + t * 256;
        if (idx < 960) sW[idx] = W[idx];
    }
    __syncthreads();

    if (tid < 150) {
        const int c = tid / 50, n = tid - c * 50;
        float m0 = 0.f, m1 = 0.f, m2 = 0.f, m3 = 0.f, m4 = 0.f;
        #pragma unroll 16
        for (int f = 0; f < 64; ++f) {              // f = j*8 + s
            const float av = cA.a[f][n];
            const int wj = (f >> 3) * 24 + c * 8 + (f & 7);
            m0 = fmaf(sW[0 * 192 + wj], av, m0);
            m1 = fmaf(sW[1 * 192 + wj], av, m1);
            m2 = fmaf(sW[2 * 192 + wj], av, m2);
            m3 = fmaf(sW[3 * 192 + wj], av, m3);
            m4 = fmaf(sW[4 * 192 + wj], av, m4);
        }
        Mgt[0 * 152 + tid] = m0;
        Mgt[1 * 152 + tid] = m1;
        Mgt[2 * 152 + tid] = m2;
        Mgt[3 * 152 + tid] = m3;
        Mgt[4 * 152 + tid] = m4;
    } else if (tid < 155) {
        const int k = tid - 150;
        Mgt[k * 152 + 150] = bias[k];
    } else if (tid < 160) {
        const int k = tid - 155;
        Mgt[k * 152 + 151] = 0.f;
    }
}

// ---------------------------------------------------------------------------
// Kernel 2: 4 threads per row, interleaved float2 (quad reads 32 contiguous
// bytes per step -> ~16 lines per wave-instr, TA-cheap). No fold: block
// prologue is 3 coalesced sweeps loading Mgt (3 KB) into LDS. Per j-step:
// 1 global float2 + 5 ds_read_b64 (4 distinct addrs, 16-lane broadcast,
// conflict-free) + 10 fma. Quad shfl_xor reduce; lane q==0 stores 20 B.
// 2048 blocks x 256 threads = 8 blocks/CU.
// ---------------------------------------------------------------------------
#define QSTEP(fi)                                                        \
    {   const float2 xv = xr[(fi)];                                      \
        const int ib = 2 * (fi);                                         \
        { const float2 mm = *(const float2*)&sMt[0 * 152 + ib];          \
          a0 = fmaf(mm.x, xv.x, a0); a0 = fmaf(mm.y, xv.y, a0); }        \
        { const float2 mm = *(const float2*)&sMt[1 * 152 + ib];          \
          a1 = fmaf(mm.x, xv.x, a1); a1 = fmaf(mm.y, xv.y, a1); }        \
        { const float2 mm = *(const float2*)&sMt[2 * 152 + ib];          \
          a2 = fmaf(mm.x, xv.x, a2); a2 = fmaf(mm.y, xv.y, a2); }        \
        { const float2 mm = *(const float2*)&sMt[3 * 152 + ib];          \
          a3 = fmaf(mm.x, xv.x, a3); a3 = fmaf(mm.y, xv.y, a3); }        \
        { const float2 mm = *(const float2*)&sMt[4 * 152 + ib];          \
          a4 = fmaf(mm.x, xv.x, a4); a4 = fmaf(mm.y, xv.y, a4); }        \
    }

__global__ __launch_bounds__(256, 4) void dwt_gemv(const float* __restrict__ x,
                                                   const float* __restrict__ Mgt,
                                                   float* __restrict__ out) {
    __shared__ float sMt[5 * 152];
    const int tid = threadIdx.x;
    #pragma unroll
    for (int t = 0; t < 3; ++t) {
        const int idx = tid + t * 256;
        if (idx < 760) sMt[idx] = Mgt[idx];
    }
    __syncthreads();

    const size_t g   = (size_t)blockIdx.x * 256 + tid;
    const size_t row = g >> 2;
    const int    q   = (int)(g & 3);
    const float2* __restrict__ xr = (const float2*)(x + row * 150);  // 8B-aligned

    float a0 = 0.f, a1 = 0.f, a2 = 0.f, a3 = 0.f, a4 = 0.f;

    // fi = 4j+q for j=0..17 (all quads), plus j=18 for q<3 -> covers 0..74
    #pragma unroll
    for (int j = 0; j < 18; ++j)
        QSTEP(4 * j + q)
    if (q < 3)
        QSTEP(72 + q)

    // quad reduction (lanes 4i..4i+3 in same wave)
    a0 += __shfl_xor(a0, 1); a0 += __shfl_xor(a0, 2);
    a1 += __shfl_xor(a1, 1); a1 += __shfl_xor(a1, 2);
    a2 += __shfl_xor(a2, 1); a2 += __shfl_xor(a2, 2);
    a3 += __shfl_xor(a3, 1); a3 += __shfl_xor(a3, 2);
    a4 += __shfl_xor(a4, 1); a4 += __shfl_xor(a4, 2);

    if (q == 0) {
        float* o = out + row * 5;
        o[0] = a0 + sMt[0 * 152 + 150];
        o[1] = a1 + sMt[1 * 152 + 150];
        o[2] = a2 + sMt[2 * 152 + 150];
        o[3] = a3 + sMt[3 * 152 + 150];
        o[4] = a4 + sMt[4 * 152 + 150];
    }
}

extern "C" void kernel_launch(void* const* d_in, const int* in_sizes, int n_in,
                              void* d_out, int out_size, void* d_ws, size_t ws_size,
                              hipStream_t stream) {
    const float* x    = (const float*)d_in[0];   // (131072, 3, 50)
    const float* W    = (const float*)d_in[1];   // (5, 192)
    const float* bias = (const float*)d_in[2];   // (5,)
    float*       out  = (float*)d_out;           // (131072, 5)
    float*       Mgt  = (float*)d_ws;            // 760 floats, [5][152]

    build_M<<<1, 256, 0, stream>>>(W, bias, Mgt);

    const int B = in_sizes[0] / 150;             // 131072
    const int grid = (B * 4) / 256;              // 2048 blocks, 8/CU
    dwt_gemv<<<grid, 256, 0, stream>>>(x, Mgt, out);
}